// Round 14
// baseline (275.134 us; speedup 1.0000x reference)
//
#include <hip/hip_runtime.h>
#include <hip/hip_bf16.h>
#include <stdint.h>

typedef __attribute__((ext_vector_type(8))) short short8;  // 8 bf16 (4 VGPRs)
typedef __attribute__((ext_vector_type(4))) float f32x4;   // 4 fp32 acc

__device__ __forceinline__ uint16_t f2bf(float f) {
    union { float f; uint32_t u; } v; v.f = f;
    uint32_t r = v.u + 0x7FFF + ((v.u >> 16) & 1);  // RNE
    return (uint16_t)(r >> 16);
}
__device__ __forceinline__ float bf2f(uint16_t u) {
    union { uint32_t u; float f; } v; v.u = ((uint32_t)u) << 16;
    return v.f;
}

template<int F32>
__device__ __forceinline__ uint4 load8(const void* p, size_t off) {
    if (F32) {
        const float* f = (const float*)p + off;
        float4 f0 = *(const float4*)f;
        float4 f1 = *(const float4*)(f + 4);
        uint4 r;
        r.x = (uint32_t)f2bf(f0.x) | ((uint32_t)f2bf(f0.y) << 16);
        r.y = (uint32_t)f2bf(f0.z) | ((uint32_t)f2bf(f0.w) << 16);
        r.z = (uint32_t)f2bf(f1.x) | ((uint32_t)f2bf(f1.y) << 16);
        r.w = (uint32_t)f2bf(f1.z) | ((uint32_t)f2bf(f1.w) << 16);
        return r;
    } else {
        return *(const uint4*)((const uint16_t*)p + off);
    }
}

// global -> LDS direct DMA, 16 B/lane; LDS dest = wave-uniform base + lane*16.
#define GLDS(gp, lp) __builtin_amdgcn_global_load_lds( \
    (const __attribute__((address_space(1))) void*)(gp), \
    (__attribute__((address_space(3))) void*)(lp), 16, 0, 0)

// ---------------------------------------------------------------------------
// cvt (weights + pos only) + mask canonicalization fused. Block 0 also
// canonicalizes the bool mask (encoding auto-detected). x converts in-qkv.
// ---------------------------------------------------------------------------
struct CvtSeg { const float* s; uint16_t* d; int n8; };
struct CvtArgs { CvtSeg seg[6]; int nseg; const void* mraw; int* mcanon; };

__global__ __launch_bounds__(256) void cvt_bf16(CvtArgs a)
{
    if (blockIdx.x == 0) {
        __shared__ int flags[3];
        const uint32_t* w = (const uint32_t*)a.mraw;
        const uint8_t* b8 = (const uint8_t*)a.mraw;
        const int t = threadIdx.x;
        if (t < 3) flags[t] = 0;
        __syncthreads();
        int fbyte = 0, ff32 = 0, fodd = 0;
        for (int i = t; i < 1024; i += 256) {
            uint32_t v = w[i];
            if (v != 0u && v != 1u && v != 0x3F800000u) fbyte = 1;
            if (v == 0x3F800000u) ff32 = 1;
            if ((i & 1) && v != 0u) fodd = 1;
        }
        if (fbyte) atomicOr(&flags[0], 1);
        if (ff32)  atomicOr(&flags[1], 1);
        if (fodd)  atomicOr(&flags[2], 1);
        __syncthreads();
        int mode;  // 0 = word, 1 = byte, 2 = int64
        if (flags[0]) mode = 1;
        else if (flags[1]) mode = 0;
        else if (!flags[2]) mode = 2;
        else mode = 0;
        for (int k = t; k < 4096; k += 256) {
            int val;
            if (mode == 1)      val = (b8[k] != 0);
            else if (mode == 2) val = (w[2 * k] != 0u);
            else                val = (w[k] != 0u);
            a.mcanon[k] = val;
        }
    }
    const int tid = blockIdx.x * 256 + threadIdx.x;
    const int stride = gridDim.x * 256;
    for (int s = 0; s < a.nseg; ++s) {
        const float* src = a.seg[s].s;
        uint16_t* dst = a.seg[s].d;
        const int n8 = a.seg[s].n8;
        if (src) {
            for (int i = tid; i < n8; i += stride)
                *(uint4*)(dst + (size_t)i * 8) = load8<1>(src, (size_t)i * 8);
        } else {
            const uint4 z = {0u, 0u, 0u, 0u};
            for (int i = tid; i < n8; i += stride)
                *(uint4*)(dst + (size_t)i * 8) = z;
        }
    }
}

// ---------------------------------------------------------------------------
// QKV GEMM, 128x128 tile, BK=64 (two 128x32 sub-tiles per operand; 64B LDS
// rows = conflict-free). A is fp32 read directly from the input and converted
// during staging: hoisted load8<1> + ds_write_b128 into the SAME 64B-row
// bf16 layout (write word-bases cycle {0,8,16,24} per 4 lanes -> exactly 8
// bank sweeps per b128, no conflict — unlike r10's fp32-row staging).
// B (weights, bf16) staged via glds. Eliminates the x pre-convert pass.
// cm 1: (B,H,T,DH); cm 2: (B,H,DH,T) via per-wave LDS transpose.
// ---------------------------------------------------------------------------
__global__ __launch_bounds__(256) void gemm128_qkv(
    const float* __restrict__ xq, const float* __restrict__ xk, const float* __restrict__ xv,
    const uint16_t* __restrict__ Wq, const uint16_t* __restrict__ Wk, const uint16_t* __restrict__ Wv,
    uint16_t* __restrict__ Qh, uint16_t* __restrict__ Khd, uint16_t* __restrict__ Vt)
{
    __shared__ alignas(16) uint16_t As[2][128 * 32];   // k-halves, bf16
    __shared__ alignas(16) uint16_t Bs[2][128 * 32];

    const int z = blockIdx.z;
    const float* A = (z == 0) ? xq : (z == 1) ? xk : xv;
    const uint16_t* B = (z == 0) ? Wq : (z == 1) ? Wk : Wv;
    uint16_t* C = (z == 0) ? Qh : (z == 1) ? Khd : Vt;
    const int cm = (z == 2) ? 2 : 1;
    const int bm = blockIdx.x, bn = blockIdx.y;
    const int K = 1024;

    const int t = threadIdx.x;
    const int lane = t & 63, wave = t >> 6;
    const int lrow = lane & 15, quad = lane >> 4;
    const int wr = (wave >> 1) * 64, wc = (wave & 1) * 64;
    const int g_row = wave * 16 + (lane >> 2);
    const int g_col = (lane & 3) * 8;
    // A staging map: thread t -> row t>>1 (0..127), col half (t&1)*16
    const int s_row = t >> 1, s_col = (t & 1) * 16;

    const f32x4 fz = {0.f, 0.f, 0.f, 0.f};
    f32x4 acc[4][4];
#pragma unroll
    for (int i = 0; i < 4; ++i)
#pragma unroll
        for (int j = 0; j < 4; ++j) acc[i][j] = fz;

    for (int k0 = 0; k0 < K; k0 += 64) {
        uint4 lo[2], hi[2];
#pragma unroll
        for (int kh = 0; kh < 2; ++kh) {  // hoist fp32 loads above barrier
            size_t off = (size_t)(bm * 128 + s_row) * K + k0 + kh * 32 + s_col;
            lo[kh] = load8<1>(A, off);
            hi[kh] = load8<1>(A, off + 8);
        }
        __syncthreads();
#pragma unroll
        for (int kh = 0; kh < 2; ++kh) {
            *(uint4*)(As[kh] + s_row * 32 + s_col)     = lo[kh];
            *(uint4*)(As[kh] + s_row * 32 + s_col + 8) = hi[kh];
            const int kk = k0 + kh * 32;
            GLDS(B + (size_t)(bn * 128 + g_row) * K + kk + g_col,      Bs[kh] + wave * 512);
            GLDS(B + (size_t)(bn * 128 + g_row + 64) * K + kk + g_col, Bs[kh] + wave * 512 + 2048);
        }
        __syncthreads();

#pragma unroll
        for (int kh = 0; kh < 2; ++kh) {
            short8 a[4], b[4];
#pragma unroll
            for (int i = 0; i < 4; ++i)
                a[i] = *(const short8*)(As[kh] + (wr + i * 16 + lrow) * 32 + quad * 8);
#pragma unroll
            for (int j = 0; j < 4; ++j)
                b[j] = *(const short8*)(Bs[kh] + (wc + j * 16 + lrow) * 32 + quad * 8);
#pragma unroll
            for (int i = 0; i < 4; ++i)
#pragma unroll
                for (int j = 0; j < 4; ++j)
                    acc[i][j] = __builtin_amdgcn_mfma_f32_16x16x32_bf16(a[i], b[j], acc[i][j], 0, 0, 0);
        }
    }

    if (cm == 2) {
        __syncthreads();
        uint16_t* scr = As[0] + wave * 1024;
#pragma unroll
        for (int i = 0; i < 4; ++i)
#pragma unroll
            for (int j = 0; j < 4; ++j) {
                uint2 pk;
                pk.x = (uint32_t)f2bf(acc[i][j][0]) | ((uint32_t)f2bf(acc[i][j][1]) << 16);
                pk.y = (uint32_t)f2bf(acc[i][j][2]) | ((uint32_t)f2bf(acc[i][j][3]) << 16);
                *(uint2*)(scr + lrow * 16 + quad * 4) = pk;
                if (lane < 32) {
                    int n = lane >> 1, m8 = (lane & 1) * 8;
                    short8 vv = *(const short8*)(scr + n * 16 + m8);
                    int ng = bn * 128 + wc + j * 16 + n;        // (h,d)
                    int hh = ng >> 6, d = ng & 63;
                    int mg = bm * 128 + wr + i * 16;            // t base
                    int bb = mg >> 10, tl = (mg & 1023) + m8;
                    *(short8*)(C + ((((size_t)bb * 16 + hh) * 64 + d) * 1024 + tl)) = vv;
                }
            }
        return;
    }

#pragma unroll
    for (int i = 0; i < 4; ++i)
#pragma unroll
        for (int j = 0; j < 4; ++j)
#pragma unroll
            for (int r = 0; r < 4; ++r) {
                // verified C/D map: row = quad*4 + reg, col = lane&15
                int m = bm * 128 + wr + i * 16 + quad * 4 + r;
                int n = bn * 128 + wc + j * 16 + lrow;
                int bb = m >> 10, tt = m & 1023, hh = n >> 6, d = n & 63;
                C[(((size_t)bb * 16 + hh) * 1024 + tt) * 64 + d] = f2bf(acc[i][j][r]);
            }
}

// ---------------------------------------------------------------------------
// Output projection, 64x64 tiles -> 1024 blocks = 4/CU (the 64x128 grid was
// 512 = 2/CU; GEMM counters showed starvation, not bandwidth). BK=64,
// waves 2x2 of 32x32, 8 MFMA + 4 glds + 8 ds_read per iter. LDS 16 KB.
// ---------------------------------------------------------------------------
__global__ __launch_bounds__(256) void gemm_out(
    const uint16_t* __restrict__ A, const uint16_t* __restrict__ B,
    float* __restrict__ C, int M, int N, int K)
{
    __shared__ alignas(16) uint16_t As[2][64 * 32];
    __shared__ alignas(16) uint16_t Bs[2][64 * 32];

    const int t = threadIdx.x;
    const int lane = t & 63, wave = t >> 6;
    const int lrow = lane & 15, quad = lane >> 4;
    const int wr = (wave >> 1) * 32, wc = (wave & 1) * 32;
    const int g_row = wave * 16 + (lane >> 2);
    const int g_col = (lane & 3) * 8;
    const int bm = blockIdx.x, bn = blockIdx.y;

    const f32x4 fz = {0.f, 0.f, 0.f, 0.f};
    f32x4 acc[2][2];
#pragma unroll
    for (int i = 0; i < 2; ++i)
#pragma unroll
        for (int j = 0; j < 2; ++j) acc[i][j] = fz;

    for (int k0 = 0; k0 < K; k0 += 64) {
        __syncthreads();
#pragma unroll
        for (int kh = 0; kh < 2; ++kh) {
            const int kk = k0 + kh * 32;
            GLDS(A + (size_t)(bm * 64 + g_row) * K + kk + g_col, As[kh] + wave * 512);
            GLDS(B + (size_t)(bn * 64 + g_row) * K + kk + g_col, Bs[kh] + wave * 512);
        }
        __syncthreads();

#pragma unroll
        for (int kh = 0; kh < 2; ++kh) {
            short8 a[2], b[2];
#pragma unroll
            for (int i = 0; i < 2; ++i)
                a[i] = *(const short8*)(As[kh] + (wr + i * 16 + lrow) * 32 + quad * 8);
#pragma unroll
            for (int j = 0; j < 2; ++j)
                b[j] = *(const short8*)(Bs[kh] + (wc + j * 16 + lrow) * 32 + quad * 8);
#pragma unroll
            for (int i = 0; i < 2; ++i)
#pragma unroll
                for (int j = 0; j < 2; ++j)
                    acc[i][j] = __builtin_amdgcn_mfma_f32_16x16x32_bf16(a[i], b[j], acc[i][j], 0, 0, 0);
        }
    }

#pragma unroll
    for (int i = 0; i < 2; ++i)
#pragma unroll
        for (int j = 0; j < 2; ++j)
#pragma unroll
            for (int r = 0; r < 4; ++r) {
                int m = bm * 64 + wr + i * 16 + quad * 4 + r;
                int n = bn * 64 + wc + j * 16 + lrow;
                C[(size_t)m * N + n] = acc[i][j][r];
            }
}

// ---------------------------------------------------------------------------
// Flash attention v7 (UNCHANGED — locally converged at ~83us after 6
// structural rounds; dbuf K/V staging, 1 barrier/iter, Pl stride 72,
// band/const split, fixed-max softmax).
// LDS: Ks 16K + Vs 16K + Qpos_l 35K + Pl 9K = 77 KB -> 2 blocks/CU.
// Qpos_l row width MUST be >= 272 (prologue writes cols up to 271).
// ---------------------------------------------------------------------------
__global__ __launch_bounds__(256) void flash_attn(
    const uint16_t* __restrict__ Qh, const uint16_t* __restrict__ Kh,
    const uint16_t* __restrict__ Vt, const uint16_t* __restrict__ pos,
    const int* __restrict__ mask, uint16_t* __restrict__ comb)
{
    const int blk = blockIdx.x;     // 0..1023
    const int bh = blk >> 4;        // b*16+h
    const int qt = blk & 15;
    const int b = bh >> 4;
    const int h = bh & 15;
    const int t = threadIdx.x;
    const int lane = t & 63;
    const int wave = t >> 6;
    const int lrow = lane & 15;
    const int quad = lane >> 4;
    const int qb = qt * 64 + wave * 16;

    __shared__ alignas(16) uint16_t Ks[2][4096];       // 2 x 8 KB
    __shared__ alignas(16) uint16_t Vs[2][4096];       // 2 x 8 KB
    __shared__ alignas(16) uint16_t Qpos_l[64][274];   // 35072 B
    __shared__ alignas(16) uint16_t Pl[4][16][72];     // 9216 B

    const uint16_t* Kp = Kh + (size_t)bh * 65536;
    const uint16_t* Vp = Vt + (size_t)bh * 65536;
    const int* mk = mask + b * 1024;

    const int sg_r = lane >> 2;
    const int sg_c = (lane & 3) * 8;
    const int hw = wave >> 1;
    const int gw = (wave & 1) * 2;

    // issue tile-0 staging first: latency hides under the pos-slab prologue
#pragma unroll
    for (int gg = 0; gg < 2; ++gg) {
        int g = gw + gg;
        GLDS(Kp + (size_t)(g * 16 + sg_r) * 64 + hw * 32 + sg_c, &Ks[0][hw * 2048 + g * 512]);
        GLDS(Vp + (size_t)(g * 16 + sg_r) * 1024 + hw * 32 + sg_c, &Vs[0][hw * 2048 + g * 512]);
    }

    const uint16_t* Qp = Qh + ((size_t)bh * 1024 + qb) * 64;
    short8 aq0 = *(const short8*)(Qp + (size_t)lrow * 64 + quad * 8);
    short8 aq1 = *(const short8*)(Qp + (size_t)lrow * 64 + 32 + quad * 8);

    const f32x4 fz = {0.f, 0.f, 0.f, 0.f};

    // ---- prologue: 16x272 pos-logit slab, B-frags from global (L2-hot) ----
#pragma unroll 4
    for (int nt = 0; nt < 17; ++nt) {
        short8 pb0 = *(const short8*)(pos + (size_t)(nt * 16 + lrow) * 64 + quad * 8);
        short8 pb1 = *(const short8*)(pos + (size_t)(nt * 16 + lrow) * 64 + 32 + quad * 8);
        f32x4 c = __builtin_amdgcn_mfma_f32_16x16x32_bf16(aq0, pb0, fz, 0, 0, 0);
        c = __builtin_amdgcn_mfma_f32_16x16x32_bf16(aq1, pb1, c, 0, 0, 0);
#pragma unroll
        for (int r = 0; r < 4; ++r)
            Qpos_l[wave * 16 + quad * 4 + r][nt * 16 + lrow] = f2bf(c[r]);
    }

    float pcl[4], pch[4];
#pragma unroll
    for (int r = 0; r < 4; ++r) {
        int ql = wave * 16 + quad * 4 + r;
        pcl[r] = bf2f(Qpos_l[ql][0])   * 0.125f;
        pch[r] = bf2f(Qpos_l[ql][256]) * 0.125f;
    }

    f32x4 o[4] = {fz, fz, fz, fz};
    float lsum[4] = {0.f, 0.f, 0.f, 0.f};

    for (int kb = 0; kb < 1024; kb += 64) {
        const int cur = (kb >> 6) & 1;
        __syncthreads();  // drains prefetch (issued last iter); guards buffers
        if (kb + 64 < 1024) {
            const int nxt = cur ^ 1;
#pragma unroll
            for (int gg = 0; gg < 2; ++gg) {
                int g = gw + gg;
                GLDS(Kp + (size_t)(kb + 64 + g * 16 + sg_r) * 64 + hw * 32 + sg_c,
                     &Ks[nxt][hw * 2048 + g * 512]);
                GLDS(Vp + (size_t)(g * 16 + sg_r) * 1024 + kb + 64 + hw * 32 + sg_c,
                     &Vs[nxt][hw * 2048 + g * 512]);
            }
        }
        const uint16_t* Kc = Ks[cur];
        const uint16_t* Vc = Vs[cur];

        f32x4 s[4];
#pragma unroll
        for (int j = 0; j < 4; ++j) {
            short8 k0 = *(const short8*)(Kc + (j * 16 + lrow) * 32 + quad * 8);
            short8 k1 = *(const short8*)(Kc + 2048 + (j * 16 + lrow) * 32 + quad * 8);
            s[j] = __builtin_amdgcn_mfma_f32_16x16x32_bf16(aq0, k0, fz, 0, 0, 0);
            s[j] = __builtin_amdgcn_mfma_f32_16x16x32_bf16(aq1, k1, s[j], 0, 0, 0);
        }

        const int diff = kb - qb;                    // wave-uniform
        if (diff <= -192 || diff >= 144) {
            const bool low = (diff <= -192);
#pragma unroll
            for (int j = 0; j < 4; ++j) {
                const int key = kb + j * 16 + lrow;
                const bool m = (mk[key] != 0);
#pragma unroll
                for (int r = 0; r < 4; ++r) {
                    float pc = low ? pcl[r] : pch[r];
                    float e = m ? 0.f : __expf(__builtin_fmaf(s[j][r], 0.125f, pc));
                    lsum[r] += e;
                    Pl[wave][quad * 4 + r][j * 16 + lrow] = f2bf(e);
                }
            }
        } else {
#pragma unroll
            for (int j = 0; j < 4; ++j) {
                const int key = kb + j * 16 + lrow;
                const bool m = (mk[key] != 0);
#pragma unroll
                for (int r = 0; r < 4; ++r) {
                    int q = qb + quad * 4 + r;
                    int ql = q & 63;
                    int rel = min(max(key - q, -128), 128) + 128;
                    float p = bf2f(Qpos_l[ql][rel]);
                    float e = m ? 0.f : __expf((s[j][r] + p) * 0.125f);
                    lsum[r] += e;
                    Pl[wave][quad * 4 + r][j * 16 + lrow] = f2bf(e);
                }
            }
        }
        short8 ap0 = *(const short8*)(&Pl[wave][lrow][quad * 8]);
        short8 ap1 = *(const short8*)(&Pl[wave][lrow][32 + quad * 8]);

#pragma unroll
        for (int dt = 0; dt < 4; ++dt) {
            short8 v0 = *(const short8*)(Vc + (dt * 16 + lrow) * 32 + quad * 8);
            short8 v1 = *(const short8*)(Vc + 2048 + (dt * 16 + lrow) * 32 + quad * 8);
            o[dt] = __builtin_amdgcn_mfma_f32_16x16x32_bf16(ap0, v0, o[dt], 0, 0, 0);
            o[dt] = __builtin_amdgcn_mfma_f32_16x16x32_bf16(ap1, v1, o[dt], 0, 0, 0);
        }
    }

#pragma unroll
    for (int off = 1; off < 16; off <<= 1)
#pragma unroll
        for (int r = 0; r < 4; ++r)
            lsum[r] += __shfl_xor(lsum[r], off);

    float inv[4];
#pragma unroll
    for (int r = 0; r < 4; ++r) inv[r] = 1.0f / lsum[r];

#pragma unroll
    for (int dt = 0; dt < 4; ++dt)
#pragma unroll
        for (int r = 0; r < 4; ++r) {
            size_t row = (size_t)b * 1024 + qb + quad * 4 + r;
            size_t col = (size_t)h * 64 + dt * 16 + lrow;
            comb[row * 1024 + col] = f2bf(o[dt][r] * inv[r]);
        }
}

// ---------------------------------------------------------------------------
// ws layout (~34.2 MB): Qh 8 | Khd 8 | Vt 8 | comb 8 | W*4 8 | posb | canon
// ---------------------------------------------------------------------------
extern "C" void kernel_launch(void* const* d_in, const int* in_sizes, int n_in,
                              void* d_out, int out_size, void* d_ws, size_t ws_size,
                              hipStream_t stream)
{
    const float* x_q = (const float*)d_in[0];
    const float* x_k = (const float*)d_in[1];
    const float* x_v = (const float*)d_in[2];
    const void*  msk = d_in[3];
    const float* Wq  = (const float*)d_in[4];
    const float* Wk  = (const float*)d_in[5];
    const float* Wv  = (const float*)d_in[6];
    const float* Wo  = (const float*)d_in[7];
    const float* pos = (const float*)d_in[8];

    char* ws = (char*)d_ws;
    const size_t MB = 1u << 20;
    uint16_t* Qh   = (uint16_t*)(ws);
    uint16_t* Khd  = (uint16_t*)(ws + 8 * MB);
    uint16_t* Vt   = (uint16_t*)(ws + 16 * MB);
    uint16_t* comb = (uint16_t*)(ws + 24 * MB);
    uint16_t* Wqb  = (uint16_t*)(ws + 32 * MB);
    uint16_t* Wkb  = (uint16_t*)(ws + 34 * MB);
    uint16_t* Wvb  = (uint16_t*)(ws + 36 * MB);
    uint16_t* Wob  = (uint16_t*)(ws + 38 * MB);
    uint16_t* posb = (uint16_t*)(ws + 40 * MB);       // 272x64 bf16, rows 257+ zero
    int*      canon = (int*)(ws + 40 * MB + 65536);

    CvtArgs ca{};
    int ns = 0;
    ca.seg[ns++] = {Wq, Wqb, 131072};
    ca.seg[ns++] = {Wk, Wkb, 131072};
    ca.seg[ns++] = {Wv, Wvb, 131072};
    ca.seg[ns++] = {Wo, Wob, 131072};
    ca.seg[ns++] = {pos, posb, 2056};              // 257*64/8
    ca.seg[ns++] = {nullptr, posb + 16448, 120};   // zero rows 257..271
    ca.nseg = ns;
    ca.mraw = msk;
    ca.mcanon = canon;
    cvt_bf16<<<dim3(64), dim3(256), 0, stream>>>(ca);

    // Fused Q/K/V projections (fp32 x converted in-kernel): 32x8x3 = 768 blocks
    gemm128_qkv<<<dim3(32, 8, 3), dim3(256), 0, stream>>>(
        x_q, x_k, x_v, Wqb, Wkb, Wvb, Qh, Khd, Vt);

    flash_attn<<<dim3(1024), dim3(256), 0, stream>>>(Qh, Khd, Vt, posb, canon, comb);

    // Output projection: comb(bf16) @ Wo_b^T -> fp32 d_out (64x64, 1024 blocks)
    gemm_out<<<dim3(64, 16), dim3(256), 0, stream>>>(
        comb, Wob, (float*)d_out, 4096, 1024, 1024);
}

// Round 15
// 243.694 us; speedup vs baseline: 1.1290x; 1.1290x over previous
//
#include <hip/hip_runtime.h>
#include <hip/hip_bf16.h>
#include <stdint.h>

typedef __attribute__((ext_vector_type(8))) short short8;  // 8 bf16 (4 VGPRs)
typedef __attribute__((ext_vector_type(4))) float f32x4;   // 4 fp32 acc

__device__ __forceinline__ uint16_t f2bf(float f) {
    union { float f; uint32_t u; } v; v.f = f;
    uint32_t r = v.u + 0x7FFF + ((v.u >> 16) & 1);  // RNE
    return (uint16_t)(r >> 16);
}
__device__ __forceinline__ float bf2f(uint16_t u) {
    union { uint32_t u; float f; } v; v.u = ((uint32_t)u) << 16;
    return v.f;
}

template<int F32>
__device__ __forceinline__ uint4 load8(const void* p, size_t off) {
    if (F32) {
        const float* f = (const float*)p + off;
        float4 f0 = *(const float4*)f;
        float4 f1 = *(const float4*)(f + 4);
        uint4 r;
        r.x = (uint32_t)f2bf(f0.x) | ((uint32_t)f2bf(f0.y) << 16);
        r.y = (uint32_t)f2bf(f0.z) | ((uint32_t)f2bf(f0.w) << 16);
        r.z = (uint32_t)f2bf(f1.x) | ((uint32_t)f2bf(f1.y) << 16);
        r.w = (uint32_t)f2bf(f1.z) | ((uint32_t)f2bf(f1.w) << 16);
        return r;
    } else {
        return *(const uint4*)((const uint16_t*)p + off);
    }
}

// global -> LDS direct DMA, 16 B/lane; LDS dest = wave-uniform base + lane*16.
#define GLDS(gp, lp) __builtin_amdgcn_global_load_lds( \
    (const __attribute__((address_space(1))) void*)(gp), \
    (__attribute__((address_space(3))) void*)(lp), 16, 0, 0)

// ---------------------------------------------------------------------------
// cvt (x + weights + pos) + mask canonicalization fused (r13-proven).
// ---------------------------------------------------------------------------
struct CvtSeg { const float* s; uint16_t* d; int n8; };
struct CvtArgs { CvtSeg seg[9]; int nseg; const void* mraw; int* mcanon; };

__global__ __launch_bounds__(256) void cvt_bf16(CvtArgs a)
{
    if (blockIdx.x == 0) {
        __shared__ int flags[3];
        const uint32_t* w = (const uint32_t*)a.mraw;
        const uint8_t* b8 = (const uint8_t*)a.mraw;
        const int t = threadIdx.x;
        if (t < 3) flags[t] = 0;
        __syncthreads();
        int fbyte = 0, ff32 = 0, fodd = 0;
        for (int i = t; i < 1024; i += 256) {
            uint32_t v = w[i];
            if (v != 0u && v != 1u && v != 0x3F800000u) fbyte = 1;
            if (v == 0x3F800000u) ff32 = 1;
            if ((i & 1) && v != 0u) fodd = 1;
        }
        if (fbyte) atomicOr(&flags[0], 1);
        if (ff32)  atomicOr(&flags[1], 1);
        if (fodd)  atomicOr(&flags[2], 1);
        __syncthreads();
        int mode;  // 0 = word, 1 = byte, 2 = int64
        if (flags[0]) mode = 1;
        else if (flags[1]) mode = 0;
        else if (!flags[2]) mode = 2;
        else mode = 0;
        for (int k = t; k < 4096; k += 256) {
            int val;
            if (mode == 1)      val = (b8[k] != 0);
            else if (mode == 2) val = (w[2 * k] != 0u);
            else                val = (w[k] != 0u);
            a.mcanon[k] = val;
        }
    }
    const int tid = blockIdx.x * 256 + threadIdx.x;
    const int stride = gridDim.x * 256;
    for (int s = 0; s < a.nseg; ++s) {
        const float* src = a.seg[s].s;
        uint16_t* dst = a.seg[s].d;
        const int n8 = a.seg[s].n8;
        if (src) {
            for (int i = tid; i < n8; i += stride)
                *(uint4*)(dst + (size_t)i * 8) = load8<1>(src, (size_t)i * 8);
        } else {
            const uint4 z = {0u, 0u, 0u, 0u};
            for (int i = tid; i < n8; i += stride)
                *(uint4*)(dst + (size_t)i * 8) = z;
        }
    }
}

// ---------------------------------------------------------------------------
// QKV GEMM, 128x128 tile, BK=64 as TWO 128x32 sub-tiles per operand — exact
// r13 version (best measured). Pure-bf16 glds staging, 32 MFMA per barrier
// pair. NOTE (r9/r10/r14 lesson): never reduce MFMA-per-barrier; never stage
// fp32 rows into LDS (16-way conflict) or via in-loop vector loads (exposed
// vmcnt drain).
// ---------------------------------------------------------------------------
__global__ __launch_bounds__(256) void gemm128_qkv(
    const uint16_t* __restrict__ xq, const uint16_t* __restrict__ xk, const uint16_t* __restrict__ xv,
    const uint16_t* __restrict__ Wq, const uint16_t* __restrict__ Wk, const uint16_t* __restrict__ Wv,
    uint16_t* __restrict__ Qh, uint16_t* __restrict__ Khd, uint16_t* __restrict__ Vt)
{
    __shared__ alignas(16) uint16_t As[2][128 * 32];   // k-halves
    __shared__ alignas(16) uint16_t Bs[2][128 * 32];

    const int z = blockIdx.z;
    const uint16_t* A = (z == 0) ? xq : (z == 1) ? xk : xv;
    const uint16_t* B = (z == 0) ? Wq : (z == 1) ? Wk : Wv;
    uint16_t* C = (z == 0) ? Qh : (z == 1) ? Khd : Vt;
    const int cm = (z == 2) ? 2 : 1;
    const int bm = blockIdx.x, bn = blockIdx.y;
    const int K = 1024;

    const int t = threadIdx.x;
    const int lane = t & 63, wave = t >> 6;
    const int lrow = lane & 15, quad = lane >> 4;
    const int wr = (wave >> 1) * 64, wc = (wave & 1) * 64;
    const int g_row = wave * 16 + (lane >> 2);
    const int g_col = (lane & 3) * 8;

    const f32x4 fz = {0.f, 0.f, 0.f, 0.f};
    f32x4 acc[4][4];
#pragma unroll
    for (int i = 0; i < 4; ++i)
#pragma unroll
        for (int j = 0; j < 4; ++j) acc[i][j] = fz;

    for (int k0 = 0; k0 < K; k0 += 64) {
        __syncthreads();
#pragma unroll
        for (int kh = 0; kh < 2; ++kh) {
            const int kk = k0 + kh * 32;
            GLDS(A + (size_t)(bm * 128 + g_row) * K + kk + g_col,      As[kh] + wave * 512);
            GLDS(A + (size_t)(bm * 128 + g_row + 64) * K + kk + g_col, As[kh] + wave * 512 + 2048);
            GLDS(B + (size_t)(bn * 128 + g_row) * K + kk + g_col,      Bs[kh] + wave * 512);
            GLDS(B + (size_t)(bn * 128 + g_row + 64) * K + kk + g_col, Bs[kh] + wave * 512 + 2048);
        }
        __syncthreads();

#pragma unroll
        for (int kh = 0; kh < 2; ++kh) {
            short8 a[4], b[4];
#pragma unroll
            for (int i = 0; i < 4; ++i)
                a[i] = *(const short8*)(As[kh] + (wr + i * 16 + lrow) * 32 + quad * 8);
#pragma unroll
            for (int j = 0; j < 4; ++j)
                b[j] = *(const short8*)(Bs[kh] + (wc + j * 16 + lrow) * 32 + quad * 8);
#pragma unroll
            for (int i = 0; i < 4; ++i)
#pragma unroll
                for (int j = 0; j < 4; ++j)
                    acc[i][j] = __builtin_amdgcn_mfma_f32_16x16x32_bf16(a[i], b[j], acc[i][j], 0, 0, 0);
        }
    }

    if (cm == 2) {
        __syncthreads();
        uint16_t* scr = As[0] + wave * 1024;
#pragma unroll
        for (int i = 0; i < 4; ++i)
#pragma unroll
            for (int j = 0; j < 4; ++j) {
                uint2 pk;
                pk.x = (uint32_t)f2bf(acc[i][j][0]) | ((uint32_t)f2bf(acc[i][j][1]) << 16);
                pk.y = (uint32_t)f2bf(acc[i][j][2]) | ((uint32_t)f2bf(acc[i][j][3]) << 16);
                *(uint2*)(scr + lrow * 16 + quad * 4) = pk;
                if (lane < 32) {
                    int n = lane >> 1, m8 = (lane & 1) * 8;
                    short8 vv = *(const short8*)(scr + n * 16 + m8);
                    int ng = bn * 128 + wc + j * 16 + n;        // (h,d)
                    int hh = ng >> 6, d = ng & 63;
                    int mg = bm * 128 + wr + i * 16;            // t base
                    int bb = mg >> 10, tl = (mg & 1023) + m8;
                    *(short8*)(C + ((((size_t)bb * 16 + hh) * 64 + d) * 1024 + tl)) = vv;
                }
            }
        return;
    }

#pragma unroll
    for (int i = 0; i < 4; ++i)
#pragma unroll
        for (int j = 0; j < 4; ++j)
#pragma unroll
            for (int r = 0; r < 4; ++r) {
                // verified C/D map: row = quad*4 + reg, col = lane&15
                int m = bm * 128 + wr + i * 16 + quad * 4 + r;
                int n = bn * 128 + wc + j * 16 + lrow;
                int bb = m >> 10, tt = m & 1023, hh = n >> 6, d = n & 63;
                C[(((size_t)bb * 16 + hh) * 1024 + tt) * 64 + d] = f2bf(acc[i][j][r]);
            }
}

// ---------------------------------------------------------------------------
// Output projection, 64x128 tiles (512 blocks = 2/CU), BK=64 — exact r13
// version. 16 MFMA/iter. LDS 24KB.
// ---------------------------------------------------------------------------
__global__ __launch_bounds__(256) void gemm_out(
    const uint16_t* __restrict__ A, const uint16_t* __restrict__ B,
    float* __restrict__ C, int M, int N, int K)
{
    __shared__ alignas(16) uint16_t As[2][64 * 32];
    __shared__ alignas(16) uint16_t Bs[2][128 * 32];

    const int t = threadIdx.x;
    const int lane = t & 63, wave = t >> 6;
    const int lrow = lane & 15, quad = lane >> 4;
    const int wr = (wave >> 1) * 32, wc = (wave & 1) * 64;
    const int g_row = wave * 16 + (lane >> 2);
    const int g_col = (lane & 3) * 8;
    const int bm = blockIdx.x, bn = blockIdx.y;

    const f32x4 fz = {0.f, 0.f, 0.f, 0.f};
    f32x4 acc[2][4];
#pragma unroll
    for (int i = 0; i < 2; ++i)
#pragma unroll
        for (int j = 0; j < 4; ++j) acc[i][j] = fz;

    for (int k0 = 0; k0 < K; k0 += 64) {
        __syncthreads();
#pragma unroll
        for (int kh = 0; kh < 2; ++kh) {
            const int kk = k0 + kh * 32;
            GLDS(A + (size_t)(bm * 64 + g_row) * K + kk + g_col,       As[kh] + wave * 512);
            GLDS(B + (size_t)(bn * 128 + g_row) * K + kk + g_col,      Bs[kh] + wave * 512);
            GLDS(B + (size_t)(bn * 128 + g_row + 64) * K + kk + g_col, Bs[kh] + wave * 512 + 2048);
        }
        __syncthreads();

#pragma unroll
        for (int kh = 0; kh < 2; ++kh) {
            short8 a[2], b[4];
#pragma unroll
            for (int i = 0; i < 2; ++i)
                a[i] = *(const short8*)(As[kh] + (wr + i * 16 + lrow) * 32 + quad * 8);
#pragma unroll
            for (int j = 0; j < 4; ++j)
                b[j] = *(const short8*)(Bs[kh] + (wc + j * 16 + lrow) * 32 + quad * 8);
#pragma unroll
            for (int i = 0; i < 2; ++i)
#pragma unroll
                for (int j = 0; j < 4; ++j)
                    acc[i][j] = __builtin_amdgcn_mfma_f32_16x16x32_bf16(a[i], b[j], acc[i][j], 0, 0, 0);
        }
    }

#pragma unroll
    for (int i = 0; i < 2; ++i)
#pragma unroll
        for (int j = 0; j < 4; ++j)
#pragma unroll
            for (int r = 0; r < 4; ++r) {
                int m = bm * 64 + wr + i * 16 + quad * 4 + r;
                int n = bn * 128 + wc + j * 16 + lrow;
                C[(size_t)m * N + n] = acc[i][j][r];
            }
}

// ---------------------------------------------------------------------------
// Flash attention v8 — r12/r13 structure + XCD-aware block swizzle.
// The 16 blocks sharing one (b,h)'s 256KB K/V previously scattered round-
// robin over all 8 XCDs (8x L2 duplication; FETCH 70MB vs ~26MB ideal). Now
// bh = (blk&7)*8 + ((blk>>3)>>4), qt = (blk>>3)&15: all 16 blocks of a bh
// share blk%8 -> same XCD under round-robin dispatch. Speed heuristic only —
// correctness is mapping-independent (every (bh,qt) covered exactly once).
// LDS: Ks 16K + Vs 16K + Qpos_l 35K + Pl 9K = 77 KB -> 2 blocks/CU.
// Qpos_l row width MUST be >= 272 (prologue writes cols up to 271).
// ---------------------------------------------------------------------------
__global__ __launch_bounds__(256) void flash_attn(
    const uint16_t* __restrict__ Qh, const uint16_t* __restrict__ Kh,
    const uint16_t* __restrict__ Vt, const uint16_t* __restrict__ pos,
    const int* __restrict__ mask, uint16_t* __restrict__ comb)
{
    const int blk = blockIdx.x;     // 0..1023
    const int jj = blk >> 3;        // 0..127
    const int bh = (blk & 7) * 8 + (jj >> 4);   // XCD-locality swizzle
    const int qt = jj & 15;
    const int b = bh >> 4;
    const int h = bh & 15;
    const int t = threadIdx.x;
    const int lane = t & 63;
    const int wave = t >> 6;
    const int lrow = lane & 15;
    const int quad = lane >> 4;
    const int qb = qt * 64 + wave * 16;

    __shared__ alignas(16) uint16_t Ks[2][4096];       // 2 x 8 KB
    __shared__ alignas(16) uint16_t Vs[2][4096];       // 2 x 8 KB
    __shared__ alignas(16) uint16_t Qpos_l[64][274];   // 35072 B
    __shared__ alignas(16) uint16_t Pl[4][16][72];     // 9216 B

    const uint16_t* Kp = Kh + (size_t)bh * 65536;
    const uint16_t* Vp = Vt + (size_t)bh * 65536;
    const int* mk = mask + b * 1024;

    const int sg_r = lane >> 2;
    const int sg_c = (lane & 3) * 8;
    const int hw = wave >> 1;
    const int gw = (wave & 1) * 2;

    // issue tile-0 staging first: latency hides under the pos-slab prologue
#pragma unroll
    for (int gg = 0; gg < 2; ++gg) {
        int g = gw + gg;
        GLDS(Kp + (size_t)(g * 16 + sg_r) * 64 + hw * 32 + sg_c, &Ks[0][hw * 2048 + g * 512]);
        GLDS(Vp + (size_t)(g * 16 + sg_r) * 1024 + hw * 32 + sg_c, &Vs[0][hw * 2048 + g * 512]);
    }

    const uint16_t* Qp = Qh + ((size_t)bh * 1024 + qb) * 64;
    short8 aq0 = *(const short8*)(Qp + (size_t)lrow * 64 + quad * 8);
    short8 aq1 = *(const short8*)(Qp + (size_t)lrow * 64 + 32 + quad * 8);

    const f32x4 fz = {0.f, 0.f, 0.f, 0.f};

    // ---- prologue: 16x272 pos-logit slab, B-frags from global (L2-hot) ----
#pragma unroll 4
    for (int nt = 0; nt < 17; ++nt) {
        short8 pb0 = *(const short8*)(pos + (size_t)(nt * 16 + lrow) * 64 + quad * 8);
        short8 pb1 = *(const short8*)(pos + (size_t)(nt * 16 + lrow) * 64 + 32 + quad * 8);
        f32x4 c = __builtin_amdgcn_mfma_f32_16x16x32_bf16(aq0, pb0, fz, 0, 0, 0);
        c = __builtin_amdgcn_mfma_f32_16x16x32_bf16(aq1, pb1, c, 0, 0, 0);
#pragma unroll
        for (int r = 0; r < 4; ++r)
            Qpos_l[wave * 16 + quad * 4 + r][nt * 16 + lrow] = f2bf(c[r]);
    }

    float pcl[4], pch[4];
#pragma unroll
    for (int r = 0; r < 4; ++r) {
        int ql = wave * 16 + quad * 4 + r;
        pcl[r] = bf2f(Qpos_l[ql][0])   * 0.125f;
        pch[r] = bf2f(Qpos_l[ql][256]) * 0.125f;
    }

    f32x4 o[4] = {fz, fz, fz, fz};
    float lsum[4] = {0.f, 0.f, 0.f, 0.f};

    for (int kb = 0; kb < 1024; kb += 64) {
        const int cur = (kb >> 6) & 1;
        __syncthreads();  // drains prefetch (issued last iter); guards buffers
        if (kb + 64 < 1024) {
            const int nxt = cur ^ 1;
#pragma unroll
            for (int gg = 0; gg < 2; ++gg) {
                int g = gw + gg;
                GLDS(Kp + (size_t)(kb + 64 + g * 16 + sg_r) * 64 + hw * 32 + sg_c,
                     &Ks[nxt][hw * 2048 + g * 512]);
                GLDS(Vp + (size_t)(g * 16 + sg_r) * 1024 + kb + 64 + hw * 32 + sg_c,
                     &Vs[nxt][hw * 2048 + g * 512]);
            }
        }
        const uint16_t* Kc = Ks[cur];
        const uint16_t* Vc = Vs[cur];

        f32x4 s[4];
#pragma unroll
        for (int j = 0; j < 4; ++j) {
            short8 k0 = *(const short8*)(Kc + (j * 16 + lrow) * 32 + quad * 8);
            short8 k1 = *(const short8*)(Kc + 2048 + (j * 16 + lrow) * 32 + quad * 8);
            s[j] = __builtin_amdgcn_mfma_f32_16x16x32_bf16(aq0, k0, fz, 0, 0, 0);
            s[j] = __builtin_amdgcn_mfma_f32_16x16x32_bf16(aq1, k1, s[j], 0, 0, 0);
        }

        const int diff = kb - qb;                    // wave-uniform
        if (diff <= -192 || diff >= 144) {
            const bool low = (diff <= -192);
#pragma unroll
            for (int j = 0; j < 4; ++j) {
                const int key = kb + j * 16 + lrow;
                const bool m = (mk[key] != 0);
#pragma unroll
                for (int r = 0; r < 4; ++r) {
                    float pc = low ? pcl[r] : pch[r];
                    float e = m ? 0.f : __expf(__builtin_fmaf(s[j][r], 0.125f, pc));
                    lsum[r] += e;
                    Pl[wave][quad * 4 + r][j * 16 + lrow] = f2bf(e);
                }
            }
        } else {
#pragma unroll
            for (int j = 0; j < 4; ++j) {
                const int key = kb + j * 16 + lrow;
                const bool m = (mk[key] != 0);
#pragma unroll
                for (int r = 0; r < 4; ++r) {
                    int q = qb + quad * 4 + r;
                    int ql = q & 63;
                    int rel = min(max(key - q, -128), 128) + 128;
                    float p = bf2f(Qpos_l[ql][rel]);
                    float e = m ? 0.f : __expf((s[j][r] + p) * 0.125f);
                    lsum[r] += e;
                    Pl[wave][quad * 4 + r][j * 16 + lrow] = f2bf(e);
                }
            }
        }
        short8 ap0 = *(const short8*)(&Pl[wave][lrow][quad * 8]);
        short8 ap1 = *(const short8*)(&Pl[wave][lrow][32 + quad * 8]);

#pragma unroll
        for (int dt = 0; dt < 4; ++dt) {
            short8 v0 = *(const short8*)(Vc + (dt * 16 + lrow) * 32 + quad * 8);
            short8 v1 = *(const short8*)(Vc + 2048 + (dt * 16 + lrow) * 32 + quad * 8);
            o[dt] = __builtin_amdgcn_mfma_f32_16x16x32_bf16(ap0, v0, o[dt], 0, 0, 0);
            o[dt] = __builtin_amdgcn_mfma_f32_16x16x32_bf16(ap1, v1, o[dt], 0, 0, 0);
        }
    }

#pragma unroll
    for (int off = 1; off < 16; off <<= 1)
#pragma unroll
        for (int r = 0; r < 4; ++r)
            lsum[r] += __shfl_xor(lsum[r], off);

    float inv[4];
#pragma unroll
    for (int r = 0; r < 4; ++r) inv[r] = 1.0f / lsum[r];

#pragma unroll
    for (int dt = 0; dt < 4; ++dt)
#pragma unroll
        for (int r = 0; r < 4; ++r) {
            size_t row = (size_t)b * 1024 + qb + quad * 4 + r;
            size_t col = (size_t)h * 64 + dt * 16 + lrow;
            comb[row * 1024 + col] = f2bf(o[dt][r] * inv[r]);
        }
}

// ---------------------------------------------------------------------------
// ws layout (r13-proven, ~56.1 MB; ws_size >= ~72 MB evidenced rounds 0-3):
// Qh 8 | Khd 8 | Vt 8 | xqb 8 (comb reuse) | xkb 8 | xvb 8 | W*4 8 | posb | canon
// ---------------------------------------------------------------------------
extern "C" void kernel_launch(void* const* d_in, const int* in_sizes, int n_in,
                              void* d_out, int out_size, void* d_ws, size_t ws_size,
                              hipStream_t stream)
{
    const float* x_q = (const float*)d_in[0];
    const float* x_k = (const float*)d_in[1];
    const float* x_v = (const float*)d_in[2];
    const void*  msk = d_in[3];
    const float* Wq  = (const float*)d_in[4];
    const float* Wk  = (const float*)d_in[5];
    const float* Wv  = (const float*)d_in[6];
    const float* Wo  = (const float*)d_in[7];
    const float* pos = (const float*)d_in[8];

    char* ws = (char*)d_ws;
    const size_t MB = 1u << 20;
    uint16_t* Qh   = (uint16_t*)(ws);
    uint16_t* Khd  = (uint16_t*)(ws + 8 * MB);
    uint16_t* Vt   = (uint16_t*)(ws + 16 * MB);
    uint16_t* xqb  = (uint16_t*)(ws + 24 * MB);
    uint16_t* xkb  = (uint16_t*)(ws + 32 * MB);
    uint16_t* xvb  = (uint16_t*)(ws + 40 * MB);
    uint16_t* Wqb  = (uint16_t*)(ws + 48 * MB);
    uint16_t* Wkb  = (uint16_t*)(ws + 50 * MB);
    uint16_t* Wvb  = (uint16_t*)(ws + 52 * MB);
    uint16_t* Wob  = (uint16_t*)(ws + 54 * MB);
    uint16_t* posb = (uint16_t*)(ws + 56 * MB);       // 272x64 bf16, rows 257+ zero
    int*      canon = (int*)(ws + 56 * MB + 65536);
    uint16_t* comb = xqb;  // xqb dead after projections; flash runs after them

    CvtArgs ca{};
    int ns = 0;
    ca.seg[ns++] = {x_q, xqb, 524288};
    ca.seg[ns++] = {x_k, xkb, 524288};
    ca.seg[ns++] = {x_v, xvb, 524288};
    ca.seg[ns++] = {Wq, Wqb, 131072};
    ca.seg[ns++] = {Wk, Wkb, 131072};
    ca.seg[ns++] = {Wv, Wvb, 131072};
    ca.seg[ns++] = {Wo, Wob, 131072};
    ca.seg[ns++] = {pos, posb, 2056};              // 257*64/8
    ca.seg[ns++] = {nullptr, posb + 16448, 120};   // zero rows 257..271
    ca.nseg = ns;
    ca.mraw = msk;
    ca.mcanon = canon;
    cvt_bf16<<<dim3(512), dim3(256), 0, stream>>>(ca);

    // Fused Q/K/V projections, BK=64 two-half staging: 32x8x3 = 768 blocks
    gemm128_qkv<<<dim3(32, 8, 3), dim3(256), 0, stream>>>(
        xqb, xkb, xvb, Wqb, Wkb, Wvb, Qh, Khd, Vt);

    flash_attn<<<dim3(1024), dim3(256), 0, stream>>>(Qh, Khd, Vt, posb, canon, comb);

    // Output projection: comb(bf16) @ Wo_b^T -> fp32 d_out (64x128, BK=64)
    gemm_out<<<dim3(64, 8), dim3(256), 0, stream>>>(
        comb, Wob, (float*)d_out, 4096, 1024, 1024);
}